// Round 5
// baseline (332.997 us; speedup 1.0000x reference)
//
#include <hip/hip_runtime.h>

#define TINYF 1e-8f
#define NITER 50

// Each lane owns interior rows R0..R0+2 (R0 = (t>>2)*3), cols C0..C0+11
// (C0 = (t&3)*12), stored EXTENDED: e[i][0..15] = cols C0-2 .. C0+13.
// Edge cols (0,1,14,15) mirror neighbors' interiors (zero at crop boundary).

__device__ __forceinline__ void prep(const float* w16, float* s1, float* s2) {
#pragma unroll
    for (int c = 0; c < 12; ++c) {
        s1[c] = w16[c + 1] + w16[c + 3];   // |dx|=1 pair
        s2[c] = w16[c] + w16[c + 4];       // |dx|=2 pair
    }
}

__device__ __forceinline__ void fma3(float* acc, const float* w16,
                                     const float* s1, const float* s2,
                                     float w0, float w1, float w2) {
#pragma unroll
    for (int c = 0; c < 12; ++c)
        acc[c] += w0 * w16[c + 2] + w1 * s1[c] + w2 * s2[c];
}

// 5x5 symmetric conv. kRC = weight(|dy|=R)(|dx|=C). tXY/bXY are the same
// triples pre-zeroed for lanes whose above/below halo rows are out of range.
__device__ __forceinline__ void conv25(const float (&e)[3][16], int upL, int dnL,
    float k00, float k01, float k02,
    float k10, float k11, float k12,
    float k20, float k21, float k22,
    float t10, float t11, float t12, float t20, float t21, float t22,
    float b10, float b11, float b12, float b20, float b21, float b22,
    float acc[3][12])
{
    float w16[16], s1[12], s2[12];
#pragma unroll
    for (int i = 0; i < 3; ++i)
#pragma unroll
        for (int c = 0; c < 12; ++c) acc[i][c] = 0.0f;

    // window row R0-2 = lane-4's row 1
#pragma unroll
    for (int k = 0; k < 16; ++k) w16[k] = __shfl(e[1][k], upL, 64);
    prep(w16, s1, s2);
    fma3(acc[0], w16, s1, s2, t20, t21, t22);
    // window row R0-1 = lane-4's row 2
#pragma unroll
    for (int k = 0; k < 16; ++k) w16[k] = __shfl(e[2][k], upL, 64);
    prep(w16, s1, s2);
    fma3(acc[0], w16, s1, s2, t10, t11, t12);
    fma3(acc[1], w16, s1, s2, t20, t21, t22);
    // own rows
    prep(e[0], s1, s2);
    fma3(acc[0], e[0], s1, s2, k00, k01, k02);
    fma3(acc[1], e[0], s1, s2, k10, k11, k12);
    fma3(acc[2], e[0], s1, s2, k20, k21, k22);
    prep(e[1], s1, s2);
    fma3(acc[0], e[1], s1, s2, k10, k11, k12);
    fma3(acc[1], e[1], s1, s2, k00, k01, k02);
    fma3(acc[2], e[1], s1, s2, k10, k11, k12);
    prep(e[2], s1, s2);
    fma3(acc[0], e[2], s1, s2, k20, k21, k22);
    fma3(acc[1], e[2], s1, s2, k10, k11, k12);
    fma3(acc[2], e[2], s1, s2, k00, k01, k02);
    // window row R0+3 = lane+4's row 0
#pragma unroll
    for (int k = 0; k < 16; ++k) w16[k] = __shfl(e[0][k], dnL, 64);
    prep(w16, s1, s2);
    fma3(acc[1], w16, s1, s2, b20, b21, b22);
    fma3(acc[2], w16, s1, s2, b10, b11, b12);
    // window row R0+4 = lane+4's row 1
#pragma unroll
    for (int k = 0; k < 16; ++k) w16[k] = __shfl(e[1][k], dnL, 64);
    prep(w16, s1, s2);
    fma3(acc[2], w16, s1, s2, b20, b21, b22);
}

// refresh the 2-col halos after interior cols (2..13) were rewritten
__device__ __forceinline__ void extend(float (&e)[3][16], int lL, int rL, int lc) {
#pragma unroll
    for (int i = 0; i < 3; ++i) {
        float l0 = __shfl(e[i][12], lL, 64);
        float l1 = __shfl(e[i][13], lL, 64);
        float r0 = __shfl(e[i][2],  rL, 64);
        float r1 = __shfl(e[i][3],  rL, 64);
        e[i][0]  = (lc == 0) ? 0.0f : l0;
        e[i][1]  = (lc == 0) ? 0.0f : l1;
        e[i][14] = (lc == 3) ? 0.0f : r0;
        e[i][15] = (lc == 3) ? 0.0f : r1;
    }
}

__device__ __forceinline__ float uni(float x) {
    return __uint_as_float(__builtin_amdgcn_readfirstlane(__float_as_uint(x)));
}

__global__ __launch_bounds__(64, 1)
void sinkhorn_shfl(const float* __restrict__ hm_gt,
                   const float* __restrict__ hm_pred,
                   const int* __restrict__ tops,
                   float* __restrict__ out) {
    const int t = threadIdx.x;
    const int blk = blockIdx.x;              // ((bi*8+rr)*5+cc)
    const int bi = blk / 40;
    const int rr = (blk / 5) % 8;
    const int cc = blk % 5;
    const int y0 = tops[(bi * 8 + rr) * 2 + 0];
    const int x0 = tops[(bi * 8 + rr) * 2 + 1];
    const float* srcA = hm_gt + (size_t)(bi * 5 + cc) * 25600;
    const float* srcB = hm_pred + (size_t)(bi * 5 + cc) * 25600;

    const int lr = t >> 2, lc = t & 3;
    const int R0 = lr * 3, C0 = lc * 12;
    const int upL = t - 4, dnL = t + 4, lL = t - 1, rL = t + 1;

    // ---- load 3x12 tiles of both crops; wave-reduce sums ----
    float va[36], vb[36];
    float sA = 0.f, sB = 0.f;
#pragma unroll
    for (int i = 0; i < 3; ++i) {
        const int g = (y0 + R0 + i) * 160 + x0 + C0;
#pragma unroll
        for (int q = 0; q < 12; ++q) {
            const float A = srcA[g + q];
            const float B = srcB[g + q];
            va[i * 12 + q] = A; vb[i * 12 + q] = B;
            sA += A; sB += B;
        }
    }
#pragma unroll
    for (int o = 1; o < 64; o <<= 1) {
        sA += __shfl_xor(sA, o, 64);
        sB += __shfl_xor(sB, o, 64);
    }
    const float rA = 1.0f / (sA + TINYF);
    const float rB = 1.0f / (sB + TINYF);
#pragma unroll
    for (int k = 0; k < 36; ++k) { va[k] *= rA; vb[k] *= rB; }

    // ---- Gibbs weights (wave-uniform -> SGPRs) ----
    const float e10 = uni(expf(-1.0f / 0.1f));
    const float e2  = uni(expf(-sqrtf(2.0f) / 0.1f));
    const float e20 = uni(expf(-2.0f / 0.1f));
    const float e5  = uni(expf(-sqrtf(5.0f) / 0.1f));
    const float e8  = uni(expf(-sqrtf(8.0f) / 0.1f));
    // vertical-halo-masked copies (VGPR, per-lane)
    const bool vt = (lr != 0), vbo = (lr != 15);
    const float t10 = vt ? e10 : 0.f, t11 = vt ? e2 : 0.f, t12 = vt ? e5 : 0.f;
    const float t20 = vt ? e20 : 0.f, t21 = vt ? e5 : 0.f, t22 = vt ? e8 : 0.f;
    const float b10 = vbo ? e10 : 0.f, b11 = vbo ? e2 : 0.f, b12 = vbo ? e5 : 0.f;
    const float b20 = vbo ? e20 : 0.f, b21 = vbo ? e5 : 0.f, b22 = vbo ? e8 : 0.f;

    // ---- u0 = 1/n, extended ----
    float eu[3][16], ev[3][16];
    const float u0 = 1.0f / 2304.0f;
#pragma unroll
    for (int i = 0; i < 3; ++i) {
#pragma unroll
        for (int k = 0; k < 16; ++k) eu[i][k] = u0;
        eu[i][0] = eu[i][1] = (lc == 0) ? 0.f : u0;
        eu[i][14] = eu[i][15] = (lc == 3) ? 0.f : u0;
    }

    // ---- Sinkhorn iterations (no LDS, no barriers) ----
#pragma unroll 1
    for (int it = 0; it < NITER; ++it) {
        float acc[3][12];
        conv25(eu, upL, dnL, 1.0f, e10, e20, e10, e2, e5, e20, e5, e8,
               t10, t11, t12, t20, t21, t22, b10, b11, b12, b20, b21, b22, acc);
#pragma unroll
        for (int i = 0; i < 3; ++i)
#pragma unroll
            for (int c = 0; c < 12; ++c)
                ev[i][c + 2] = vb[i * 12 + c] *
                    __builtin_amdgcn_rcpf(acc[i][c] + TINYF);
        extend(ev, lL, rL, lc);

        conv25(ev, upL, dnL, 1.0f, e10, e20, e10, e2, e5, e20, e5, e8,
               t10, t11, t12, t20, t21, t22, b10, b11, b12, b20, b21, b22, acc);
#pragma unroll
        for (int i = 0; i < 3; ++i)
#pragma unroll
            for (int c = 0; c < 12; ++c)
                eu[i][c + 2] = va[i * 12 + c] *
                    __builtin_amdgcn_rcpf(acc[i][c] + TINYF);
        extend(eu, lL, rL, lc);
    }

    // ---- loss: (u @ M) . v, M = K .* dist ----
    const float s2f = sqrtf(2.0f), s5f = sqrtf(5.0f), s8f = sqrtf(8.0f);
    const float m01 = e10 * 1.0f, m02 = e20 * 2.0f;
    const float m11 = e2 * s2f,   m12 = e5 * s5f,  m22 = e8 * s8f;
    const float mt10 = vt ? m01 : 0.f, mt11 = vt ? m11 : 0.f, mt12 = vt ? m12 : 0.f;
    const float mt20 = vt ? m02 : 0.f, mt21 = vt ? m12 : 0.f, mt22 = vt ? m22 : 0.f;
    const float mb10 = vbo ? m01 : 0.f, mb11 = vbo ? m11 : 0.f, mb12 = vbo ? m12 : 0.f;
    const float mb20 = vbo ? m02 : 0.f, mb21 = vbo ? m12 : 0.f, mb22 = vbo ? m22 : 0.f;

    float accM[3][12];
    conv25(eu, upL, dnL, 0.0f, m01, m02, m01, m11, m12, m02, m12, m22,
           mt10, mt11, mt12, mt20, mt21, mt22,
           mb10, mb11, mb12, mb20, mb21, mb22, accM);
    float lsum = 0.f;
#pragma unroll
    for (int i = 0; i < 3; ++i)
#pragma unroll
        for (int c = 0; c < 12; ++c)
            lsum += accM[i][c] * ev[i][c + 2];

#pragma unroll
    for (int o = 1; o < 64; o <<= 1) lsum += __shfl_xor(lsum, o, 64);
    if (t == 0) atomicAdd(out, lsum);
}

extern "C" void kernel_launch(void* const* d_in, const int* in_sizes, int n_in,
                              void* d_out, int out_size, void* d_ws, size_t ws_size,
                              hipStream_t stream) {
    (void)in_sizes; (void)n_in; (void)out_size; (void)d_ws; (void)ws_size;
    const float* hm_gt = (const float*)d_in[0];
    const float* hm_pred = (const float*)d_in[1];
    const int* tops = (const int*)d_in[2];
    float* out = (float*)d_out;

    hipMemsetAsync(out, 0, sizeof(float), stream);
    sinkhorn_shfl<<<dim3(640), dim3(64), 0, stream>>>(hm_gt, hm_pred, tops, out);
}

// Round 6
// 266.346 us; speedup vs baseline: 1.2502x; 1.2502x over previous
//
#include <hip/hip_runtime.h>

#define TINYF 1e-8f
#define NITER 50
#define HSTR  52   // halo row stride: 2-col zero pad each side of 48

__device__ __forceinline__ float bperm(int addr4, float v) {
    return __int_as_float(__builtin_amdgcn_ds_bpermute(addr4, __float_as_int(v)));
}

// 21-tap 5x5 conv (corners dropped). Lane owns strip-local rows 3lr..3lr+2 as
// x[i][0..6] = cols 3lc-2..3lc+4 (edge cols pre-zeroed at crop boundary).
// Vertical halo rows: lane+-16 bpermute; strip boundary rows from H (padded,
// zeroed pads). kRC = weight(|dy|=R, |dx|=C); k22 dropped.
__device__ __forceinline__ void conv21(
    const float (&x)[3][7], const float* __restrict__ H,
    int w, int lr, int hcol, int upA, int dnA,
    float k00, float k01, float k02,
    float k10, float k11, float k12,
    float k20, float k21,
    float acc[3][3])
{
    float r0[7], r1[7], r5[7], r6[7];
#pragma unroll
    for (int k = 0; k < 7; ++k) {
        r0[k] = bperm(upA, x[1][k]);
        r1[k] = bperm(upA, x[2][k]);
        r5[k] = bperm(dnA, x[0][k]);
        r6[k] = bperm(dnA, x[1][k]);
    }
    if (lr == 0) {            // strip-top halo rows from wave above (or crop edge)
        if (w > 0) {
            const float* h = H + ((w - 1) * 4 + 2) * HSTR + hcol;
#pragma unroll
            for (int k = 0; k < 7; ++k) { r0[k] = h[k]; r1[k] = h[k + HSTR]; }
        } else {
#pragma unroll
            for (int k = 0; k < 7; ++k) { r0[k] = 0.f; r1[k] = 0.f; }
        }
    }
    if (lr == 3) {            // strip-bottom halo rows from wave below
        if (w < 3) {
            const float* h = H + ((w + 1) * 4 + 0) * HSTR + hcol;
#pragma unroll
            for (int k = 0; k < 7; ++k) { r5[k] = h[k]; r6[k] = h[k + HSTR]; }
        } else {
#pragma unroll
            for (int k = 0; k < 7; ++k) { r5[k] = 0.f; r6[k] = 0.f; }
        }
    }

#pragma unroll
    for (int i = 0; i < 3; ++i)
#pragma unroll
        for (int c = 0; c < 3; ++c) acc[i][c] = 0.f;

    const float* rows[7] = { r0, r1, x[0], x[1], x[2], r5, r6 };
#pragma unroll
    for (int j = 0; j < 7; ++j) {
        const float* r = rows[j];
        float a1[3], a2[3];
#pragma unroll
        for (int c = 0; c < 3; ++c) a1[c] = r[c + 1] + r[c + 3];
        if (j >= 1 && j <= 5) {
#pragma unroll
            for (int c = 0; c < 3; ++c) a2[c] = r[c] + r[c + 4];
        }
#pragma unroll
        for (int i = 0; i < 3; ++i) {
            const int d = (j - 2 - i < 0) ? (i + 2 - j) : (j - 2 - i);
            if (d > 2) continue;
            if (d == 0) {
#pragma unroll
                for (int c = 0; c < 3; ++c)
                    acc[i][c] += k00 * r[c + 2] + k01 * a1[c] + k02 * a2[c];
            } else if (d == 1) {
#pragma unroll
                for (int c = 0; c < 3; ++c)
                    acc[i][c] += k10 * r[c + 2] + k11 * a1[c] + k12 * a2[c];
            } else {
#pragma unroll
                for (int c = 0; c < 3; ++c)
                    acc[i][c] += k20 * r[c + 2] + k21 * a1[c];
            }
        }
    }
}

__global__ __launch_bounds__(256, 3)
void sinkhorn_hybrid(const float* __restrict__ hm_gt,
                     const float* __restrict__ hm_pred,
                     const int* __restrict__ tops,
                     float* __restrict__ out) {
    __shared__ __align__(16) float Hu[4 * 4 * HSTR];
    __shared__ __align__(16) float Hv[4 * 4 * HSTR];
    __shared__ float sred[8];

    const int t = threadIdx.x;
    const int w = t >> 6;                 // wave 0..3 -> strip rows 12w..12w+11
    const int l = t & 63;
    const int lr = l >> 4, lc = l & 15;   // 4x16 lane grid, 3x3 px tile

    const int blk = blockIdx.x;
    const int bi = blk / 40, rr = (blk / 5) % 8, cc = blk % 5;
    const int y0 = tops[(bi * 8 + rr) * 2 + 0];
    const int x0 = tops[(bi * 8 + rr) * 2 + 1];
    const float* srcA = hm_gt + (size_t)(bi * 5 + cc) * 25600;
    const float* srcB = hm_pred + (size_t)(bi * 5 + cc) * 25600;

    const int upA = ((l - 16) & 63) << 2;
    const int dnA = ((l + 16) & 63) << 2;
    const int lA  = ((l - 1) & 63) << 2;
    const int rA  = ((l + 1) & 63) << 2;
    const int hcol = 3 * lc;              // halo read start (padded index of col 3lc-2)

    // zero halo buffers (pads stay zero forever)
    for (int p = t; p < 4 * 4 * HSTR; p += 256) { Hu[p] = 0.f; Hv[p] = 0.f; }

    // ---- load 3x3 tiles; block-reduce sums ----
    const int gr = y0 + 12 * w + 3 * lr;
    const int gc = x0 + 3 * lc;
    float va[3][3], vb[3][3];
    float sA = 0.f, sB = 0.f;
#pragma unroll
    for (int i = 0; i < 3; ++i)
#pragma unroll
        for (int c = 0; c < 3; ++c) {
            const float A = srcA[(gr + i) * 160 + gc + c];
            const float B = srcB[(gr + i) * 160 + gc + c];
            va[i][c] = A; vb[i][c] = B;
            sA += A; sB += B;
        }
#pragma unroll
    for (int o = 1; o < 64; o <<= 1) {
        sA += __shfl_xor(sA, o, 64);
        sB += __shfl_xor(sB, o, 64);
    }
    if (l == 0) { sred[w] = sA; sred[4 + w] = sB; }
    __syncthreads();
    sA = sred[0] + sred[1] + sred[2] + sred[3];
    sB = sred[4] + sred[5] + sred[6] + sred[7];
    const float nA = 1.0f / (sA + TINYF);
    const float nB = 1.0f / (sB + TINYF);
#pragma unroll
    for (int i = 0; i < 3; ++i)
#pragma unroll
        for (int c = 0; c < 3; ++c) { va[i][c] *= nA; vb[i][c] *= nB; }

    // ---- u0 = 1/n (extended, crop-edge cols zeroed) ----
    float xu[3][7], xv[3][7];
    const float u0 = 1.0f / 2304.0f;
#pragma unroll
    for (int i = 0; i < 3; ++i) {
#pragma unroll
        for (int k = 0; k < 7; ++k) xu[i][k] = u0;
        if (lc == 0)  { xu[i][0] = 0.f; xu[i][1] = 0.f; }
        if (lc == 15) { xu[i][5] = 0.f; xu[i][6] = 0.f; }
    }
    if (lr == 0) {
        float* h = Hu + (w * 4 + 0) * HSTR + 2 + 3 * lc;
#pragma unroll
        for (int c = 0; c < 3; ++c) { h[c] = xu[0][c + 2]; h[HSTR + c] = xu[1][c + 2]; }
    }
    if (lr == 3) {
        float* h = Hu + (w * 4 + 2) * HSTR + 2 + 3 * lc;
#pragma unroll
        for (int c = 0; c < 3; ++c) { h[c] = xu[1][c + 2]; h[HSTR + c] = xu[2][c + 2]; }
    }
    __syncthreads();

    // Gibbs weights (constant-folded)
    const float e10 = expf(-1.0f / 0.1f);
    const float e2  = expf(-sqrtf(2.0f) / 0.1f);
    const float e20 = expf(-2.0f / 0.1f);
    const float e5  = expf(-sqrtf(5.0f) / 0.1f);

    // ---- Sinkhorn iterations ----
#pragma unroll 1
    for (int it = 0; it < NITER; ++it) {
        float acc[3][3];
        conv21(xu, Hu, w, lr, hcol, upA, dnA,
               1.0f, e10, e20, e10, e2, e5, e20, e5, acc);
#pragma unroll
        for (int i = 0; i < 3; ++i)
#pragma unroll
            for (int c = 0; c < 3; ++c)
                xv[i][c + 2] = vb[i][c] * __builtin_amdgcn_rcpf(acc[i][c] + TINYF);
#pragma unroll
        for (int i = 0; i < 3; ++i) {
            const float h0 = bperm(lA, xv[i][3]);
            const float h1 = bperm(lA, xv[i][4]);
            const float h2 = bperm(rA, xv[i][2]);
            const float h3 = bperm(rA, xv[i][3]);
            xv[i][0] = (lc == 0)  ? 0.f : h0;
            xv[i][1] = (lc == 0)  ? 0.f : h1;
            xv[i][5] = (lc == 15) ? 0.f : h2;
            xv[i][6] = (lc == 15) ? 0.f : h3;
        }
        if (lr == 0) {
            float* h = Hv + (w * 4 + 0) * HSTR + 2 + 3 * lc;
#pragma unroll
            for (int c = 0; c < 3; ++c) { h[c] = xv[0][c + 2]; h[HSTR + c] = xv[1][c + 2]; }
        }
        if (lr == 3) {
            float* h = Hv + (w * 4 + 2) * HSTR + 2 + 3 * lc;
#pragma unroll
            for (int c = 0; c < 3; ++c) { h[c] = xv[1][c + 2]; h[HSTR + c] = xv[2][c + 2]; }
        }
        __syncthreads();

        conv21(xv, Hv, w, lr, hcol, upA, dnA,
               1.0f, e10, e20, e10, e2, e5, e20, e5, acc);
#pragma unroll
        for (int i = 0; i < 3; ++i)
#pragma unroll
            for (int c = 0; c < 3; ++c)
                xu[i][c + 2] = va[i][c] * __builtin_amdgcn_rcpf(acc[i][c] + TINYF);
#pragma unroll
        for (int i = 0; i < 3; ++i) {
            const float h0 = bperm(lA, xu[i][3]);
            const float h1 = bperm(lA, xu[i][4]);
            const float h2 = bperm(rA, xu[i][2]);
            const float h3 = bperm(rA, xu[i][3]);
            xu[i][0] = (lc == 0)  ? 0.f : h0;
            xu[i][1] = (lc == 0)  ? 0.f : h1;
            xu[i][5] = (lc == 15) ? 0.f : h2;
            xu[i][6] = (lc == 15) ? 0.f : h3;
        }
        if (lr == 0) {
            float* h = Hu + (w * 4 + 0) * HSTR + 2 + 3 * lc;
#pragma unroll
            for (int c = 0; c < 3; ++c) { h[c] = xu[0][c + 2]; h[HSTR + c] = xu[1][c + 2]; }
        }
        if (lr == 3) {
            float* h = Hu + (w * 4 + 2) * HSTR + 2 + 3 * lc;
#pragma unroll
            for (int c = 0; c < 3; ++c) { h[c] = xu[1][c + 2]; h[HSTR + c] = xu[2][c + 2]; }
        }
        __syncthreads();
    }

    // ---- loss: (u @ M) . v, M = K .* dist (center 0, corners dropped) ----
    const float s2f = sqrtf(2.0f), s5f = sqrtf(5.0f);
    float accM[3][3];
    conv21(xu, Hu, w, lr, hcol, upA, dnA,
           0.0f, e10, e20 * 2.0f, e10, e2 * s2f, e5 * s5f, e20 * 2.0f, e5 * s5f,
           accM);
    float lsum = 0.f;
#pragma unroll
    for (int i = 0; i < 3; ++i)
#pragma unroll
        for (int c = 0; c < 3; ++c)
            lsum += accM[i][c] * xv[i][c + 2];

#pragma unroll
    for (int o = 1; o < 64; o <<= 1) lsum += __shfl_xor(lsum, o, 64);
    if (l == 0) atomicAdd(out, lsum);
}

extern "C" void kernel_launch(void* const* d_in, const int* in_sizes, int n_in,
                              void* d_out, int out_size, void* d_ws, size_t ws_size,
                              hipStream_t stream) {
    (void)in_sizes; (void)n_in; (void)out_size; (void)d_ws; (void)ws_size;
    const float* hm_gt = (const float*)d_in[0];
    const float* hm_pred = (const float*)d_in[1];
    const int* tops = (const int*)d_in[2];
    float* out = (float*)d_out;

    hipMemsetAsync(out, 0, sizeof(float), stream);
    sinkhorn_hybrid<<<dim3(640), dim3(256), 0, stream>>>(hm_gt, hm_pred, tops, out);
}